// Round 5
// baseline (562.085 us; speedup 1.0000x reference)
//
#include <hip/hip_runtime.h>
#include <cstdint>
#include <cstddef>

// Problem constants (match reference)
constexpr int Bc = 32;    // batch
constexpr int Sc = 512;   // source length
constexpr int Hc = 256;   // hidden
constexpr int Fc = 256;   // filter
constexpr int Tc = 2048;  // max mel length
constexpr int Kc = 3;     // conv kernel
constexpr float EPSc = 1e-5f;

// MFMA types
typedef __attribute__((ext_vector_type(8))) short bf16x8;
typedef __attribute__((ext_vector_type(4))) float f32x4;
typedef unsigned long long ull;
struct alignas(16) U16 { ull a, b; };

// LDS strides (shorts)
constexpr int ALD = 264;
constexpr int OLD = 268;

// Weight tensor: [co][k*256+ci] bf16, row stride 768
constexpr int KW = 768;
constexpr int KW16 = 16 * KW;               // 12288
constexpr size_t WTSZ = (size_t)Fc * KW;    // shorts per prepped tensor

// ---- output layout (flat f32) ----
constexpr size_t O_OUT   = 0;                                   // (B,T,H)
constexpr size_t O_PP    = O_OUT  + (size_t)Bc*Tc*Hc;           // (B,T)
constexpr size_t O_EP    = O_PP   + (size_t)Bc*Tc;              // (B,T)
constexpr size_t O_LOGD  = O_EP   + (size_t)Bc*Tc;              // (B,S)
constexpr size_t O_DUR   = O_LOGD + (size_t)Bc*Sc;              // (B,S)
constexpr size_t O_MLEN  = O_DUR  + (size_t)Bc*Sc;              // (B,)
constexpr size_t O_MMASK = O_MLEN + (size_t)Bc;                 // (B,T)

// ---- workspace layout (bytes) ----
constexpr size_t W_CUM = 0;                 // int[B*S]
constexpr size_t W_MEL = 0x10000;           // int[B]
constexpr size_t W_IDX = 0x10100;           // int[B*T]
constexpr size_t W_WT  = 0x60000;           // short[6][256][768] = 2.25MB
constexpr size_t W_BUF = 0x2C0000;          // bf16 buffers
constexpr size_t BUFB  = (size_t)Bc * Tc * Fc * 2;   // 32MB per buffer
// dur-path intermediate (8.4MB) lives inside the o_out region (written last).

__device__ __forceinline__ short f2bf(float f) {
  union { float f; unsigned u; } a; a.f = f;
  unsigned r = a.u + 0x7FFFu + ((a.u >> 16) & 1u);   // RNE
  return (short)(r >> 16);
}

// ============================================================
// 0) weight prep: w[k][ci][co] f32 -> w_t[co][k*256+ci] bf16, 6 tensors
// ============================================================
__global__ __launch_bounds__(256) void wprep_kernel(
    const float* __restrict__ pit, const float* __restrict__ ene,
    const float* __restrict__ dur, short* __restrict__ wt) {
  __shared__ float tile[32][33];
  int z = blockIdx.z;                         // pred*2 + layer
  const float* base = (z >> 1) == 0 ? pit : (z >> 1) == 1 ? ene : dur;
  const float* w = base + (size_t)(z & 1) * Kc * Fc * Fc;   // [768][256]
  short* out = wt + (size_t)z * WTSZ;                        // [256][768]
  int kci0 = blockIdx.x * 32, co0 = blockIdx.y * 32;
  int j = threadIdx.x & 31, i0 = threadIdx.x >> 5;
  #pragma unroll
  for (int p = 0; p < 4; p++) {
    int i = i0 + p * 8;
    tile[i][j] = w[(size_t)(kci0 + i) * Fc + co0 + j];
  }
  __syncthreads();
  #pragma unroll
  for (int p = 0; p < 4; p++) {
    int i = i0 + p * 8;
    out[(size_t)(co0 + i) * KW + kci0 + j] = f2bf(tile[j][i]);
  }
}

// ============================================================
// 1) per-batch inclusive scan of durations + dur/mel_len outputs
// ============================================================
__global__ void scan_kernel(const int* __restrict__ dur, int* __restrict__ cum,
                            int* __restrict__ mel_i, float* __restrict__ dur_out,
                            float* __restrict__ mlen_out) {
  int b = blockIdx.x;
  int lane = threadIdx.x;                 // blockDim.x == 64
  const int per = Sc / 64;                // 8
  int base = b * Sc + lane * per;
  int v[per];
  int s = 0;
  #pragma unroll
  for (int i = 0; i < per; i++) { v[i] = dur[base + i]; s += v[i]; }
  int pre = s;
  #pragma unroll
  for (int d = 1; d < 64; d <<= 1) {
    int o = __shfl_up(pre, d, 64);
    if (lane >= d) pre += o;
  }
  int run = pre - s;
  #pragma unroll
  for (int i = 0; i < per; i++) {
    run += v[i];
    cum[base + i] = run;
    dur_out[base + i] = (float)v[i];
  }
  if (lane == 63) { mel_i[b] = run; mlen_out[b] = (float)run; }
}

// ============================================================
// 2) searchsorted(cum, t, 'right') -> idx ; mel_mask output
// ============================================================
__global__ void idx_kernel(const int* __restrict__ cum, const int* __restrict__ mel_i,
                           int* __restrict__ idx, float* __restrict__ mmask) {
  int gid = blockIdx.x * blockDim.x + threadIdx.x;   // B*T threads
  int b = gid / Tc, t = gid % Tc;
  const int* c = cum + b * Sc;
  int lo = 0, hi = Sc;
  while (lo < hi) {
    int mid = (lo + hi) >> 1;
    if (c[mid] <= t) lo = mid + 1; else hi = mid;
  }
  int i = lo > (Sc - 1) ? (Sc - 1) : lo;
  idx[gid] = i;
  mmask[gid] = (t < mel_i[b]) ? 0.0f : 1.0f;
}

// ============================================================
// MEGA layer-1: z=0 pitch (gather, N=T), z=1 energy (gather, N=T),
//               z=2 duration (direct, N=S). conv+bias+ReLU+LN -> bf16 buf.
// All three paths are independent -> one launch, 2304 live blocks.
// ============================================================
__global__ __launch_bounds__(256) void conv1_mega_kernel(
    const float* __restrict__ x,
    const float* __restrict__ scP, const float* __restrict__ scE,
    const float* __restrict__ pc1_w, const float* __restrict__ pc1_b,
    const float* __restrict__ ec1_w, const float* __restrict__ ec1_b,
    const int* __restrict__ idx, const int* __restrict__ mel_i,
    const short* __restrict__ wt6,
    const float* __restrict__ cbP, const float* __restrict__ lngP, const float* __restrict__ lnbP,
    const float* __restrict__ cbE, const float* __restrict__ lngE, const float* __restrict__ lnbE,
    const float* __restrict__ cbD, const float* __restrict__ lngD, const float* __restrict__ lnbD,
    short* __restrict__ bufP, short* __restrict__ bufE, short* __restrict__ bufD) {
  const int z = blockIdx.z;
  if (z == 2 && blockIdx.x >= (Sc / 64)) return;

  __shared__ short a_lds[66 * ALD];
  __shared__ int s_idx[66];
  __shared__ float s_sc[66];
  __shared__ float part_s[64][4];
  __shared__ float part_s2[64][4];
  __shared__ float smean[64], srstd[64];

  const bool GATHER = (z < 2);
  const int N = GATHER ? Tc : Sc;
  const float* sc  = (z == 0) ? scP  : scE;
  const float* scw = (z == 0) ? pc1_w : ec1_w;
  const float* scb = (z == 0) ? pc1_b : ec1_b;
  const short* wt = wt6 + (size_t)(z * 2) * WTSZ;
  const float* cb  = (z == 0) ? cbP  : (z == 1) ? cbE  : cbD;
  const float* lng = (z == 0) ? lngP : (z == 1) ? lngE : lngD;
  const float* lnb = (z == 0) ? lnbP : (z == 1) ? lnbE : lnbD;
  short* hout = (z == 0) ? bufP : (z == 1) ? bufE : bufD;

  const int tid = threadIdx.x;
  const int b = blockIdx.y;
  const int t0 = blockIdx.x * 64;
  const int lane = tid & 63, wv = tid >> 6;
  const int l15 = lane & 15, quad = lane >> 4;

  // ---- phase A: idx/sc preload ----
  if (GATHER) {
    if (tid < 66) {
      int t = t0 + tid - 1;
      bool v = (t >= 0 && t < N && t < mel_i[b]);
      int i = v ? idx[b * Tc + t] : -1;
      s_idx[tid] = i;
      s_sc[tid] = v ? sc[b * Sc + i] : 0.0f;
    }
    __syncthreads();
  }

  // ---- phase B: branch-free batched row staging ----
  {
    const int r0 = tid >> 6;
    const int c4 = (tid & 63) * 4;
    float4 scw4 = {0, 0, 0, 0}, scb4 = {0, 0, 0, 0};
    if (GATHER) {
      scw4 = *(const float4*)(scw + c4);
      scb4 = *(const float4*)(scb + c4);
    }
    #pragma unroll
    for (int it = 0; it < 17; it++) {
      int r = it * 4 + r0;
      if (r < 66) {
        float4 v = {0, 0, 0, 0};
        if (GATHER) {
          int i = s_idx[r];
          int is = i < 0 ? 0 : i;
          float4 xv = *(const float4*)(x + ((size_t)b * Sc + is) * Hc + c4);
          float s_ = s_sc[r];
          if (i >= 0) {
            v.x = xv.x + s_ * scw4.x + scb4.x;
            v.y = xv.y + s_ * scw4.y + scb4.y;
            v.z = xv.z + s_ * scw4.z + scb4.z;
            v.w = xv.w + s_ * scw4.w + scb4.w;
          }
        } else {
          int t = t0 + r - 1;
          int ts = t < 0 ? 0 : (t > N - 1 ? N - 1 : t);
          float4 xv = *(const float4*)(x + ((size_t)b * N + ts) * Hc + c4);
          if (t >= 0 && t < N) v = xv;
        }
        uint2 pk;
        pk.x = (unsigned)(unsigned short)f2bf(v.x) |
               ((unsigned)(unsigned short)f2bf(v.y) << 16);
        pk.y = (unsigned)(unsigned short)f2bf(v.z) |
               ((unsigned)(unsigned short)f2bf(v.w) << 16);
        *(uint2*)&a_lds[r * ALD + c4] = pk;
      }
    }
  }
  __syncthreads();

  // ---- K-loop with 3-stage B prefetch ----
  f32x4 acc[4][4];
  #pragma unroll
  for (int i = 0; i < 4; i++)
    #pragma unroll
    for (int j = 0; j < 4; j++) acc[i][j] = (f32x4){0.f, 0.f, 0.f, 0.f};

  const short* wp = wt + (size_t)(wv * 64 + l15) * KW + quad * 8;
  bf16x8 vbuf[3][4];
  #pragma unroll
  for (int nt = 0; nt < 4; nt++) {
    vbuf[0][nt] = *(const bf16x8*)(wp + nt * KW16);
    vbuf[1][nt] = *(const bf16x8*)(wp + nt * KW16 + 32);
  }

  #pragma unroll 1
  for (int kb = 0; kb < 24; kb += 3) {
    #pragma unroll
    for (int sub = 0; sub < 3; sub++) {
      int kbi = kb + sub;
      int kld = kbi + 2; if (kld > 23) kld = 23;
      #pragma unroll
      for (int nt = 0; nt < 4; nt++)
        vbuf[(sub + 2) % 3][nt] = *(const bf16x8*)(wp + nt * KW16 + kld * 32);
      const int kk = kbi >> 3, ci0 = (kbi & 7) * 32;
      bf16x8 av[4];
      #pragma unroll
      for (int mt = 0; mt < 4; mt++)
        av[mt] = *(const bf16x8*)&a_lds[(mt * 16 + l15 + kk) * ALD + ci0 + quad * 8];
      #pragma unroll
      for (int mt = 0; mt < 4; mt++)
        #pragma unroll
        for (int nt = 0; nt < 4; nt++)
          acc[mt][nt] = __builtin_amdgcn_mfma_f32_16x16x32_bf16(av[mt], vbuf[sub % 3][nt], acc[mt][nt], 0, 0, 0);
    }
  }

  // ---- epilogue: bias + ReLU + LN stats ----
  float cbv[4], gv[4], bv2[4];
  #pragma unroll
  for (int nt = 0; nt < 4; nt++) {
    int ch = wv * 64 + nt * 16 + l15;
    cbv[nt] = cb[ch]; gv[nt] = lng[ch]; bv2[nt] = lnb[ch];
  }
  #pragma unroll
  for (int mt = 0; mt < 4; mt++)
    #pragma unroll
    for (int r = 0; r < 4; r++) {
      float s = 0.f, s2 = 0.f;
      #pragma unroll
      for (int nt = 0; nt < 4; nt++) {
        float v = fmaxf(acc[mt][nt][r] + cbv[nt], 0.f);
        acc[mt][nt][r] = v;
        s += v; s2 += v * v;
      }
      #pragma unroll
      for (int d = 1; d <= 8; d <<= 1) {
        s += __shfl_xor(s, d, 64);
        s2 += __shfl_xor(s2, d, 64);
      }
      if (l15 == 0) {
        int p = mt * 16 + quad * 4 + r;
        part_s[p][wv] = s; part_s2[p][wv] = s2;
      }
    }
  __syncthreads();
  if (tid < 64) {
    float s  = part_s[tid][0] + part_s[tid][1] + part_s[tid][2] + part_s[tid][3];
    float s2 = part_s2[tid][0] + part_s2[tid][1] + part_s2[tid][2] + part_s2[tid][3];
    float m = s * (1.f / Fc);
    float var = s2 * (1.f / Fc) - m * m;
    smean[tid] = m; srstd[tid] = rsqrtf(var + EPSc);
  }
  __syncthreads();

  // ---- apply LN, stage bf16 in LDS, coalesced store ----
  #pragma unroll
  for (int mt = 0; mt < 4; mt++)
    #pragma unroll
    for (int r = 0; r < 4; r++) {
      int p = mt * 16 + quad * 4 + r;
      float m = smean[p], rs = srstd[p];
      #pragma unroll
      for (int nt = 0; nt < 4; nt++) {
        float v = (acc[mt][nt][r] - m) * rs * gv[nt] + bv2[nt];
        a_lds[p * OLD + wv * 64 + nt * 16 + l15] = f2bf(v);
      }
    }
  __syncthreads();
  {
    int p = tid >> 2, c0 = (tid & 3) * 64;
    const short* src = &a_lds[p * OLD + c0];
    short* dst = hout + ((size_t)b * N + t0 + p) * 256 + c0;
    #pragma unroll
    for (int i = 0; i < 8; i++) {
      ull lo = *(const ull*)(src + i * 8);
      ull hi = *(const ull*)(src + i * 8 + 4);
      U16 v; v.a = lo; v.b = hi;
      *(U16*)(dst + i * 8) = v;
    }
  }
}

// ============================================================
// MEGA layer-2: conv+bias+ReLU+LN+(h@lw+lb)+mask -> pred
// z=0 pitch->o_pp (mel mask), z=1 energy->o_ep (mel mask),
// z=2 duration->o_logd (src mask, N=S)
// ============================================================
__global__ __launch_bounds__(256) void conv2_mega_kernel(
    const short* __restrict__ bufP, const short* __restrict__ bufE,
    const short* __restrict__ bufD,
    const int* __restrict__ mel_i, const unsigned char* __restrict__ src_mask,
    const short* __restrict__ wt6,
    const float* __restrict__ cbP, const float* __restrict__ lngP, const float* __restrict__ lnbP,
    const float* __restrict__ lwP, const float* __restrict__ lbP,
    const float* __restrict__ cbE, const float* __restrict__ lngE, const float* __restrict__ lnbE,
    const float* __restrict__ lwE, const float* __restrict__ lbE,
    const float* __restrict__ cbD, const float* __restrict__ lngD, const float* __restrict__ lnbD,
    const float* __restrict__ lwD, const float* __restrict__ lbD,
    float* __restrict__ o_pp, float* __restrict__ o_ep, float* __restrict__ o_logd) {
  const int z = blockIdx.z;
  if (z == 2 && blockIdx.x >= (Sc / 64)) return;

  __shared__ short a_lds[66 * ALD];
  __shared__ float part_s[64][4];
  __shared__ float part_s2[64][4];
  __shared__ float part_p[64][4];
  __shared__ float smean[64], srstd[64];

  const bool MASK_MEL = (z < 2);
  const int N = MASK_MEL ? Tc : Sc;
  const short* hin = (z == 0) ? bufP : (z == 1) ? bufE : bufD;
  const short* wt = wt6 + (size_t)(z * 2 + 1) * WTSZ;
  const float* cb  = (z == 0) ? cbP  : (z == 1) ? cbE  : cbD;
  const float* lng = (z == 0) ? lngP : (z == 1) ? lngE : lngD;
  const float* lnb = (z == 0) ? lnbP : (z == 1) ? lnbE : lnbD;
  const float* lw  = (z == 0) ? lwP  : (z == 1) ? lwE  : lwD;
  const float* lb  = (z == 0) ? lbP  : (z == 1) ? lbE  : lbD;
  float* pred = (z == 0) ? o_pp : (z == 1) ? o_ep : o_logd;

  const int tid = threadIdx.x;
  const int b = blockIdx.y;
  const int t0 = blockIdx.x * 64;
  const int lane = tid & 63, wv = tid >> 6;
  const int l15 = lane & 15, quad = lane >> 4;

  // ---- stage bf16 rows (branch-free clamped loads) ----
  {
    int r0 = tid >> 5, c0 = (tid & 31) * 8;
    #pragma unroll
    for (int it = 0; it < 9; it++) {
      int r = it * 8 + r0;
      if (r < 66) {
        int t = t0 + r - 1;
        int ts = t < 0 ? 0 : (t > N - 1 ? N - 1 : t);
        U16 v = *(const U16*)(hin + ((size_t)b * N + ts) * 256 + c0);
        if (!(t >= 0 && t < N)) { v.a = 0; v.b = 0; }
        *(U16*)&a_lds[r * ALD + c0] = v;
      }
    }
  }
  __syncthreads();

  // ---- K-loop with 3-stage B prefetch ----
  f32x4 acc[4][4];
  #pragma unroll
  for (int i = 0; i < 4; i++)
    #pragma unroll
    for (int j = 0; j < 4; j++) acc[i][j] = (f32x4){0.f, 0.f, 0.f, 0.f};

  const short* wp = wt + (size_t)(wv * 64 + l15) * KW + quad * 8;
  bf16x8 vbuf[3][4];
  #pragma unroll
  for (int nt = 0; nt < 4; nt++) {
    vbuf[0][nt] = *(const bf16x8*)(wp + nt * KW16);
    vbuf[1][nt] = *(const bf16x8*)(wp + nt * KW16 + 32);
  }

  #pragma unroll 1
  for (int kb = 0; kb < 24; kb += 3) {
    #pragma unroll
    for (int sub = 0; sub < 3; sub++) {
      int kbi = kb + sub;
      int kld = kbi + 2; if (kld > 23) kld = 23;
      #pragma unroll
      for (int nt = 0; nt < 4; nt++)
        vbuf[(sub + 2) % 3][nt] = *(const bf16x8*)(wp + nt * KW16 + kld * 32);
      const int kk = kbi >> 3, ci0 = (kbi & 7) * 32;
      bf16x8 av[4];
      #pragma unroll
      for (int mt = 0; mt < 4; mt++)
        av[mt] = *(const bf16x8*)&a_lds[(mt * 16 + l15 + kk) * ALD + ci0 + quad * 8];
      #pragma unroll
      for (int mt = 0; mt < 4; mt++)
        #pragma unroll
        for (int nt = 0; nt < 4; nt++)
          acc[mt][nt] = __builtin_amdgcn_mfma_f32_16x16x32_bf16(av[mt], vbuf[sub % 3][nt], acc[mt][nt], 0, 0, 0);
    }
  }

  // ---- epilogue: bias + ReLU + LN stats ----
  float cbv[4], gv[4], bv2[4], lwv[4];
  #pragma unroll
  for (int nt = 0; nt < 4; nt++) {
    int ch = wv * 64 + nt * 16 + l15;
    cbv[nt] = cb[ch]; gv[nt] = lng[ch]; bv2[nt] = lnb[ch]; lwv[nt] = lw[ch];
  }
  #pragma unroll
  for (int mt = 0; mt < 4; mt++)
    #pragma unroll
    for (int r = 0; r < 4; r++) {
      float s = 0.f, s2 = 0.f;
      #pragma unroll
      for (int nt = 0; nt < 4; nt++) {
        float v = fmaxf(acc[mt][nt][r] + cbv[nt], 0.f);
        acc[mt][nt][r] = v;
        s += v; s2 += v * v;
      }
      #pragma unroll
      for (int d = 1; d <= 8; d <<= 1) {
        s += __shfl_xor(s, d, 64);
        s2 += __shfl_xor(s2, d, 64);
      }
      if (l15 == 0) {
        int p = mt * 16 + quad * 4 + r;
        part_s[p][wv] = s; part_s2[p][wv] = s2;
      }
    }
  __syncthreads();
  if (tid < 64) {
    float s  = part_s[tid][0] + part_s[tid][1] + part_s[tid][2] + part_s[tid][3];
    float s2 = part_s2[tid][0] + part_s2[tid][1] + part_s2[tid][2] + part_s2[tid][3];
    float m = s * (1.f / Fc);
    float var = s2 * (1.f / Fc) - m * m;
    smean[tid] = m; srstd[tid] = rsqrtf(var + EPSc);
  }
  __syncthreads();

  // ---- LN apply + projection reduce ----
  #pragma unroll
  for (int mt = 0; mt < 4; mt++)
    #pragma unroll
    for (int r = 0; r < 4; r++) {
      int p = mt * 16 + quad * 4 + r;
      float m = smean[p], rs = srstd[p];
      float s = 0.f;
      #pragma unroll
      for (int nt = 0; nt < 4; nt++) {
        float v = (acc[mt][nt][r] - m) * rs * gv[nt] + bv2[nt];
        s += v * lwv[nt];
      }
      #pragma unroll
      for (int d = 1; d <= 8; d <<= 1) s += __shfl_xor(s, d, 64);
      if (l15 == 0) part_p[p][wv] = s;
    }
  __syncthreads();
  if (tid < 64) {
    float o = part_p[tid][0] + part_p[tid][1] + part_p[tid][2] + part_p[tid][3] + lb[0];
    int t = t0 + tid;
    bool masked;
    if (MASK_MEL) masked = !(t < mel_i[b]);
    else          masked = (src_mask[b * N + t] != 0);
    pred[(size_t)b * N + t] = masked ? 0.f : o;
  }
}

// ============================================================
// out = xe + pp*pc2_w + pc2_b + ep*ec2_w + ec2_b  (float4, 4 rows/block)
// ============================================================
__global__ __launch_bounds__(256) void final_kernel(
    const float* __restrict__ x, const int* __restrict__ idx,
    const int* __restrict__ mel_i,
    const float* __restrict__ pp, const float* __restrict__ ep,
    const float* __restrict__ pc2_w, const float* __restrict__ pc2_b,
    const float* __restrict__ ec2_w, const float* __restrict__ ec2_b,
    float* __restrict__ out) {
  int bt = blockIdx.x * 4 + (threadIdx.x >> 6);
  int lane = threadIdx.x & 63;
  int b = bt >> 11, t = bt & (Tc - 1);
  int c4 = lane * 4;
  int i = idx[bt];
  bool val = t < mel_i[b];
  float4 xv = *(const float4*)(x + ((size_t)b * Sc + i) * Hc + c4);
  float p = pp[bt], e = ep[bt];
  float4 pw = *(const float4*)(pc2_w + c4);
  float4 pb = *(const float4*)(pc2_b + c4);
  float4 ew = *(const float4*)(ec2_w + c4);
  float4 eb = *(const float4*)(ec2_b + c4);
  float4 o;
  o.x = (val ? xv.x : 0.f) + p * pw.x + pb.x + e * ew.x + eb.x;
  o.y = (val ? xv.y : 0.f) + p * pw.y + pb.y + e * ew.y + eb.y;
  o.z = (val ? xv.z : 0.f) + p * pw.z + pb.z + e * ew.z + eb.z;
  o.w = (val ? xv.w : 0.f) + p * pw.w + pb.w + e * ew.w + eb.w;
  *(float4*)(out + (size_t)bt * Hc + c4) = o;
}

// ============================================================
extern "C" void kernel_launch(void* const* d_in, const int* in_sizes, int n_in,
                              void* d_out, int out_size, void* d_ws, size_t ws_size,
                              hipStream_t stream) {
  const float* x          = (const float*)d_in[0];
  const unsigned char* sm = (const unsigned char*)d_in[1];
  const float* src_pitch  = (const float*)d_in[3];
  const float* src_energy = (const float*)d_in[4];
  const int*   src_dur    = (const int*)d_in[5];

  const float* dur_cw = (const float*)d_in[7];
  const float* dur_cb = (const float*)d_in[8];
  const float* dur_lng= (const float*)d_in[9];
  const float* dur_lnb= (const float*)d_in[10];
  const float* dur_lw = (const float*)d_in[11];
  const float* dur_lb = (const float*)d_in[12];

  const float* pit_cw = (const float*)d_in[13];
  const float* pit_cb = (const float*)d_in[14];
  const float* pit_lng= (const float*)d_in[15];
  const float* pit_lnb= (const float*)d_in[16];
  const float* pit_lw = (const float*)d_in[17];
  const float* pit_lb = (const float*)d_in[18];

  const float* ene_cw = (const float*)d_in[19];
  const float* ene_cb = (const float*)d_in[20];
  const float* ene_lng= (const float*)d_in[21];
  const float* ene_lnb= (const float*)d_in[22];
  const float* ene_lw = (const float*)d_in[23];
  const float* ene_lb = (const float*)d_in[24];

  const float* pc1_w = (const float*)d_in[25];
  const float* pc1_b = (const float*)d_in[26];
  const float* pc2_w = (const float*)d_in[27];
  const float* pc2_b = (const float*)d_in[28];
  const float* ec1_w = (const float*)d_in[29];
  const float* ec1_b = (const float*)d_in[30];
  const float* ec2_w = (const float*)d_in[31];
  const float* ec2_b = (const float*)d_in[32];

  float* out = (float*)d_out;
  float* o_out   = out + O_OUT;
  float* o_pp    = out + O_PP;
  float* o_ep    = out + O_EP;
  float* o_logd  = out + O_LOGD;
  float* o_dur   = out + O_DUR;
  float* o_mlen  = out + O_MLEN;
  float* o_mmask = out + O_MMASK;

  char* ws = (char*)d_ws;
  int*   w_cum = (int*)(ws + W_CUM);
  int*   w_mel = (int*)(ws + W_MEL);
  int*   w_idx = (int*)(ws + W_IDX);
  short* w_wt  = (short*)(ws + W_WT);
  short* w_bufP = (short*)(ws + W_BUF);
  short* w_bufE = (short*)(ws + W_BUF + BUFB);
  short* w_bufD = (short*)o_out;   // dur intermediate (8.4MB) in o_out (written last)

  // 0) weight prep
  wprep_kernel<<<dim3(24, 8, 6), 256, 0, stream>>>(pit_cw, ene_cw, dur_cw, w_wt);

  // 1) scan + dur/mel_len outputs
  scan_kernel<<<Bc, 64, 0, stream>>>(src_dur, w_cum, w_mel, o_dur, o_mlen);

  // 2) searchsorted + mel_mask output
  idx_kernel<<<(Bc * Tc) / 256, 256, 0, stream>>>(w_cum, w_mel, w_idx, o_mmask);

  // 3) all three layer-1 passes in one launch (z = pitch / energy / dur)
  conv1_mega_kernel<<<dim3(Tc / 64, Bc, 3), 256, 0, stream>>>(
      x, src_pitch, src_energy, pc1_w, pc1_b, ec1_w, ec1_b,
      w_idx, w_mel, w_wt,
      pit_cb, pit_lng, pit_lnb,
      ene_cb, ene_lng, ene_lnb,
      dur_cb, dur_lng, dur_lnb,
      w_bufP, w_bufE, w_bufD);

  // 4) all three layer-2+proj passes in one launch
  conv2_mega_kernel<<<dim3(Tc / 64, Bc, 3), 256, 0, stream>>>(
      w_bufP, w_bufE, w_bufD, w_mel, sm, w_wt,
      pit_cb + Fc, pit_lng + Fc, pit_lnb + Fc, pit_lw, pit_lb,
      ene_cb + Fc, ene_lng + Fc, ene_lnb + Fc, ene_lw, ene_lb,
      dur_cb + Fc, dur_lng + Fc, dur_lnb + Fc, dur_lw, dur_lb,
      o_pp, o_ep, o_logd);

  // 5) final output
  final_kernel<<<(Bc * Tc) / 4, 256, 0, stream>>>(
      x, w_idx, w_mel, o_pp, o_ep, pc2_w, pc2_b, ec2_w, ec2_b, o_out);
}

// Round 6
// 476.447 us; speedup vs baseline: 1.1797x; 1.1797x over previous
//
#include <hip/hip_runtime.h>
#include <cstdint>
#include <cstddef>

// Problem constants (match reference)
constexpr int Bc = 32;    // batch
constexpr int Sc = 512;   // source length
constexpr int Hc = 256;   // hidden
constexpr int Fc = 256;   // filter
constexpr int Tc = 2048;  // max mel length
constexpr int Kc = 3;     // conv kernel
constexpr float EPSc = 1e-5f;

// MFMA types
typedef __attribute__((ext_vector_type(8))) short bf16x8;
typedef __attribute__((ext_vector_type(4))) float f32x4;
typedef unsigned long long ull;
struct alignas(16) U16 { ull a, b; };

// LDS strides (shorts)
constexpr int ALD = 264;   // A-tile row stride (132 dw, %32=4 -> 2-way max, free)
constexpr int OLD = 268;   // output staging row stride

// Block tile: M=128 rows x 256 co, 8 waves (512 thr), wave tile 64x64
constexpr int MT = 128;
constexpr int AR = MT + 2;          // 130 staged rows

// Weight tensor: [co][k*256+ci] bf16, row stride 768
constexpr int KW = 768;
constexpr int KW16 = 16 * KW;               // 12288
constexpr size_t WTSZ = (size_t)Fc * KW;    // shorts per prepped tensor

// ---- output layout (flat f32) ----
constexpr size_t O_OUT   = 0;                                   // (B,T,H)
constexpr size_t O_PP    = O_OUT  + (size_t)Bc*Tc*Hc;           // (B,T)
constexpr size_t O_EP    = O_PP   + (size_t)Bc*Tc;              // (B,T)
constexpr size_t O_LOGD  = O_EP   + (size_t)Bc*Tc;              // (B,S)
constexpr size_t O_DUR   = O_LOGD + (size_t)Bc*Sc;              // (B,S)
constexpr size_t O_MLEN  = O_DUR  + (size_t)Bc*Sc;              // (B,)
constexpr size_t O_MMASK = O_MLEN + (size_t)Bc;                 // (B,T)

// ---- workspace layout (bytes) ----
constexpr size_t W_CUM = 0;                 // int[B*S]
constexpr size_t W_MEL = 0x10000;           // int[B]
constexpr size_t W_IDX = 0x10100;           // int[B*T]
constexpr size_t W_WT  = 0x60000;           // short[6][256][768] = 2.25MB
constexpr size_t W_BUF = 0x2C0000;          // bf16 buffers
constexpr size_t BUFB  = (size_t)Bc * Tc * Fc * 2;   // 32MB per buffer
// dur-path intermediate (8.4MB) lives inside the o_out region (written last).

__device__ __forceinline__ short f2bf(float f) {
  union { float f; unsigned u; } a; a.f = f;
  unsigned r = a.u + 0x7FFFu + ((a.u >> 16) & 1u);   // RNE
  return (short)(r >> 16);
}

// ============================================================
// 0) weight prep: w[k][ci][co] f32 -> w_t[co][k*256+ci] bf16, 6 tensors
// ============================================================
__global__ __launch_bounds__(256) void wprep_kernel(
    const float* __restrict__ pit, const float* __restrict__ ene,
    const float* __restrict__ dur, short* __restrict__ wt) {
  __shared__ float tile[32][33];
  int z = blockIdx.z;                         // pred*2 + layer
  const float* base = (z >> 1) == 0 ? pit : (z >> 1) == 1 ? ene : dur;
  const float* w = base + (size_t)(z & 1) * Kc * Fc * Fc;   // [768][256]
  short* out = wt + (size_t)z * WTSZ;                        // [256][768]
  int kci0 = blockIdx.x * 32, co0 = blockIdx.y * 32;
  int j = threadIdx.x & 31, i0 = threadIdx.x >> 5;
  #pragma unroll
  for (int p = 0; p < 4; p++) {
    int i = i0 + p * 8;
    tile[i][j] = w[(size_t)(kci0 + i) * Fc + co0 + j];
  }
  __syncthreads();
  #pragma unroll
  for (int p = 0; p < 4; p++) {
    int i = i0 + p * 8;
    out[(size_t)(co0 + i) * KW + kci0 + j] = f2bf(tile[j][i]);
  }
}

// ============================================================
// 1) per-batch inclusive scan of durations + dur/mel_len outputs
// ============================================================
__global__ void scan_kernel(const int* __restrict__ dur, int* __restrict__ cum,
                            int* __restrict__ mel_i, float* __restrict__ dur_out,
                            float* __restrict__ mlen_out) {
  int b = blockIdx.x;
  int lane = threadIdx.x;                 // blockDim.x == 64
  const int per = Sc / 64;                // 8
  int base = b * Sc + lane * per;
  int v[per];
  int s = 0;
  #pragma unroll
  for (int i = 0; i < per; i++) { v[i] = dur[base + i]; s += v[i]; }
  int pre = s;
  #pragma unroll
  for (int d = 1; d < 64; d <<= 1) {
    int o = __shfl_up(pre, d, 64);
    if (lane >= d) pre += o;
  }
  int run = pre - s;
  #pragma unroll
  for (int i = 0; i < per; i++) {
    run += v[i];
    cum[base + i] = run;
    dur_out[base + i] = (float)v[i];
  }
  if (lane == 63) { mel_i[b] = run; mlen_out[b] = (float)run; }
}

// ============================================================
// 2) searchsorted(cum, t, 'right') -> idx ; mel_mask output
// ============================================================
__global__ void idx_kernel(const int* __restrict__ cum, const int* __restrict__ mel_i,
                           int* __restrict__ idx, float* __restrict__ mmask) {
  int gid = blockIdx.x * blockDim.x + threadIdx.x;   // B*T threads
  int b = gid / Tc, t = gid % Tc;
  const int* c = cum + b * Sc;
  int lo = 0, hi = Sc;
  while (lo < hi) {
    int mid = (lo + hi) >> 1;
    if (c[mid] <= t) lo = mid + 1; else hi = mid;
  }
  int i = lo > (Sc - 1) ? (Sc - 1) : lo;
  idx[gid] = i;
  mmask[gid] = (t < mel_i[b]) ? 0.0f : 1.0f;
}

// ============================================================
// Layer-1: conv1d(K=3)+bias+ReLU+LN via MFMA.
// Block: 512 thr (8 waves). Tile M=128 x co=256. Wave: 64x64.
// GATHER: row t = valid*(x[b,idx[t],:] + sc*scw + scb); else direct rows.
// ============================================================
template <bool GATHER>
__global__ __launch_bounds__(512) void conv1_mfma_kernel(
    const float* __restrict__ x, const float* __restrict__ sc,
    const float* __restrict__ scw, const float* __restrict__ scb,
    const int* __restrict__ idx, const int* __restrict__ mel_i,
    const short* __restrict__ wt, const float* __restrict__ cb,
    const float* __restrict__ lng, const float* __restrict__ lnb,
    short* __restrict__ hout, int N) {
  __shared__ short a_lds[AR * ALD];          // 68.6 KB (reused for out staging)
  __shared__ int s_idx[AR];
  __shared__ float s_sc[AR];
  __shared__ float part_s[MT][4];
  __shared__ float part_s2[MT][4];
  __shared__ float smean[MT], srstd[MT];

  const int tid = threadIdx.x;
  const int b = blockIdx.y;
  const int t0 = blockIdx.x * MT;
  const int lane = tid & 63, wv = tid >> 6;       // wv 0..7
  const int l15 = lane & 15, quad = lane >> 4;
  const int m0 = (wv >> 2) * 64;                  // wave's row half
  const int co0 = (wv & 3) * 64;                  // wave's co quarter

  // ---- phase A: idx/sc preload (one latency round) ----
  if (GATHER) {
    if (tid < AR) {
      int t = t0 + tid - 1;
      bool v = (t >= 0 && t < N && t < mel_i[b]);
      int i = v ? idx[b * Tc + t] : -1;
      s_idx[tid] = i;
      s_sc[tid] = v ? sc[b * Sc + i] : 0.0f;
    }
    __syncthreads();
  }

  // ---- phase B: branch-free batched row staging (8 rows/iter) ----
  {
    const int r0 = tid >> 6;              // 0..7
    const int c4 = (tid & 63) * 4;
    float4 scw4 = {0, 0, 0, 0}, scb4 = {0, 0, 0, 0};
    if (GATHER) {
      scw4 = *(const float4*)(scw + c4);
      scb4 = *(const float4*)(scb + c4);
    }
    #pragma unroll
    for (int it = 0; it < 17; it++) {
      int r = it * 8 + r0;
      if (r < AR) {
        float4 v = {0, 0, 0, 0};
        if (GATHER) {
          int i = s_idx[r];
          int is = i < 0 ? 0 : i;
          float4 xv = *(const float4*)(x + ((size_t)b * Sc + is) * Hc + c4);
          float s_ = s_sc[r];
          if (i >= 0) {
            v.x = xv.x + s_ * scw4.x + scb4.x;
            v.y = xv.y + s_ * scw4.y + scb4.y;
            v.z = xv.z + s_ * scw4.z + scb4.z;
            v.w = xv.w + s_ * scw4.w + scb4.w;
          }
        } else {
          int t = t0 + r - 1;
          int ts = t < 0 ? 0 : (t > N - 1 ? N - 1 : t);
          float4 xv = *(const float4*)(x + ((size_t)b * N + ts) * Hc + c4);
          if (t >= 0 && t < N) v = xv;
        }
        uint2 pk;
        pk.x = (unsigned)(unsigned short)f2bf(v.x) |
               ((unsigned)(unsigned short)f2bf(v.y) << 16);
        pk.y = (unsigned)(unsigned short)f2bf(v.z) |
               ((unsigned)(unsigned short)f2bf(v.w) << 16);
        *(uint2*)&a_lds[r * ALD + c4] = pk;
      }
    }
  }
  __syncthreads();

  // ---- K-loop with 3-stage B prefetch ----
  f32x4 acc[4][4];
  #pragma unroll
  for (int i = 0; i < 4; i++)
    #pragma unroll
    for (int j = 0; j < 4; j++) acc[i][j] = (f32x4){0.f, 0.f, 0.f, 0.f};

  const short* wp = wt + (size_t)(co0 + l15) * KW + quad * 8;
  bf16x8 vbuf[3][4];
  #pragma unroll
  for (int nt = 0; nt < 4; nt++) {
    vbuf[0][nt] = *(const bf16x8*)(wp + nt * KW16);
    vbuf[1][nt] = *(const bf16x8*)(wp + nt * KW16 + 32);
  }

  #pragma unroll 1
  for (int kb = 0; kb < 24; kb += 3) {
    #pragma unroll
    for (int sub = 0; sub < 3; sub++) {
      int kbi = kb + sub;
      int kld = kbi + 2; if (kld > 23) kld = 23;
      #pragma unroll
      for (int nt = 0; nt < 4; nt++)
        vbuf[(sub + 2) % 3][nt] = *(const bf16x8*)(wp + nt * KW16 + kld * 32);
      const int kk = kbi >> 3, ci0 = (kbi & 7) * 32;
      bf16x8 av[4];
      #pragma unroll
      for (int mt = 0; mt < 4; mt++)
        av[mt] = *(const bf16x8*)&a_lds[(m0 + mt * 16 + l15 + kk) * ALD + ci0 + quad * 8];
      #pragma unroll
      for (int mt = 0; mt < 4; mt++)
        #pragma unroll
        for (int nt = 0; nt < 4; nt++)
          acc[mt][nt] = __builtin_amdgcn_mfma_f32_16x16x32_bf16(av[mt], vbuf[sub % 3][nt], acc[mt][nt], 0, 0, 0);
    }
  }

  // ---- epilogue: bias + ReLU + LN stats (128 rows x 4 co-waves) ----
  float cbv[4], gv[4], bv2[4];
  #pragma unroll
  for (int nt = 0; nt < 4; nt++) {
    int ch = co0 + nt * 16 + l15;
    cbv[nt] = cb[ch]; gv[nt] = lng[ch]; bv2[nt] = lnb[ch];
  }
  #pragma unroll
  for (int mt = 0; mt < 4; mt++)
    #pragma unroll
    for (int r = 0; r < 4; r++) {
      float s = 0.f, s2 = 0.f;
      #pragma unroll
      for (int nt = 0; nt < 4; nt++) {
        float v = fmaxf(acc[mt][nt][r] + cbv[nt], 0.f);
        acc[mt][nt][r] = v;
        s += v; s2 += v * v;
      }
      #pragma unroll
      for (int d = 1; d <= 8; d <<= 1) {
        s += __shfl_xor(s, d, 64);
        s2 += __shfl_xor(s2, d, 64);
      }
      if (l15 == 0) {
        int p = m0 + mt * 16 + quad * 4 + r;
        part_s[p][wv & 3] = s; part_s2[p][wv & 3] = s2;
      }
    }
  __syncthreads();
  if (tid < MT) {
    float s  = part_s[tid][0] + part_s[tid][1] + part_s[tid][2] + part_s[tid][3];
    float s2 = part_s2[tid][0] + part_s2[tid][1] + part_s2[tid][2] + part_s2[tid][3];
    float m = s * (1.f / Fc);
    float var = s2 * (1.f / Fc) - m * m;
    smean[tid] = m; srstd[tid] = rsqrtf(var + EPSc);
  }
  __syncthreads();

  // ---- apply LN, stage bf16 in LDS (stride OLD), coalesced store ----
  #pragma unroll
  for (int mt = 0; mt < 4; mt++)
    #pragma unroll
    for (int r = 0; r < 4; r++) {
      int p = m0 + mt * 16 + quad * 4 + r;
      float m = smean[p], rs = srstd[p];
      #pragma unroll
      for (int nt = 0; nt < 4; nt++) {
        float v = (acc[mt][nt][r] - m) * rs * gv[nt] + bv2[nt];
        a_lds[p * OLD + co0 + nt * 16 + l15] = f2bf(v);
      }
    }
  __syncthreads();
  {
    int p = tid >> 2, c0 = (tid & 3) * 64;          // 128 rows x 4 chunks
    const short* src = &a_lds[p * OLD + c0];
    short* dst = hout + ((size_t)b * N + t0 + p) * 256 + c0;
    #pragma unroll
    for (int i = 0; i < 8; i++) {
      ull lo = *(const ull*)(src + i * 8);
      ull hi = *(const ull*)(src + i * 8 + 4);
      U16 v; v.a = lo; v.b = hi;
      *(U16*)(dst + i * 8) = v;
    }
  }
}

// ============================================================
// Layer-2: conv+bias+ReLU+LN+(h@lw+lb)+mask -> pred.
// Block: 512 thr (8 waves), M=128 x co=256.
// ============================================================
template <bool MASK_MEL>
__global__ __launch_bounds__(512) void conv2_proj_mfma_kernel(
    const short* __restrict__ hin, const int* __restrict__ mel_i,
    const unsigned char* __restrict__ src_mask,
    const short* __restrict__ wt, const float* __restrict__ cb,
    const float* __restrict__ lng, const float* __restrict__ lnb,
    const float* __restrict__ lw, const float* __restrict__ lb,
    float* __restrict__ pred, int N) {
  __shared__ short a_lds[AR * ALD];
  __shared__ float part_s[MT][4];
  __shared__ float part_s2[MT][4];
  __shared__ float part_p[MT][4];
  __shared__ float smean[MT], srstd[MT];

  const int tid = threadIdx.x;
  const int b = blockIdx.y;
  const int t0 = blockIdx.x * MT;
  const int lane = tid & 63, wv = tid >> 6;
  const int l15 = lane & 15, quad = lane >> 4;
  const int m0 = (wv >> 2) * 64;
  const int co0 = (wv & 3) * 64;

  // ---- stage bf16 rows (branch-free clamped loads, 16 rows/iter) ----
  {
    int r0 = tid >> 5, c0 = (tid & 31) * 8;
    #pragma unroll
    for (int it = 0; it < 9; it++) {
      int r = it * 16 + r0;
      if (r < AR) {
        int t = t0 + r - 1;
        int ts = t < 0 ? 0 : (t > N - 1 ? N - 1 : t);
        U16 v = *(const U16*)(hin + ((size_t)b * N + ts) * 256 + c0);
        if (!(t >= 0 && t < N)) { v.a = 0; v.b = 0; }
        *(U16*)&a_lds[r * ALD + c0] = v;
      }
    }
  }
  __syncthreads();

  // ---- K-loop with 3-stage B prefetch ----
  f32x4 acc[4][4];
  #pragma unroll
  for (int i = 0; i < 4; i++)
    #pragma unroll
    for (int j = 0; j < 4; j++) acc[i][j] = (f32x4){0.f, 0.f, 0.f, 0.f};

  const short* wp = wt + (size_t)(co0 + l15) * KW + quad * 8;
  bf16x8 vbuf[3][4];
  #pragma unroll
  for (int nt = 0; nt < 4; nt++) {
    vbuf[0][nt] = *(const bf16x8*)(wp + nt * KW16);
    vbuf[1][nt] = *(const bf16x8*)(wp + nt * KW16 + 32);
  }

  #pragma unroll 1
  for (int kb = 0; kb < 24; kb += 3) {
    #pragma unroll
    for (int sub = 0; sub < 3; sub++) {
      int kbi = kb + sub;
      int kld = kbi + 2; if (kld > 23) kld = 23;
      #pragma unroll
      for (int nt = 0; nt < 4; nt++)
        vbuf[(sub + 2) % 3][nt] = *(const bf16x8*)(wp + nt * KW16 + kld * 32);
      const int kk = kbi >> 3, ci0 = (kbi & 7) * 32;
      bf16x8 av[4];
      #pragma unroll
      for (int mt = 0; mt < 4; mt++)
        av[mt] = *(const bf16x8*)&a_lds[(m0 + mt * 16 + l15 + kk) * ALD + ci0 + quad * 8];
      #pragma unroll
      for (int mt = 0; mt < 4; mt++)
        #pragma unroll
        for (int nt = 0; nt < 4; nt++)
          acc[mt][nt] = __builtin_amdgcn_mfma_f32_16x16x32_bf16(av[mt], vbuf[sub % 3][nt], acc[mt][nt], 0, 0, 0);
    }
  }

  // ---- epilogue: bias + ReLU + LN stats ----
  float cbv[4], gv[4], bv2[4], lwv[4];
  #pragma unroll
  for (int nt = 0; nt < 4; nt++) {
    int ch = co0 + nt * 16 + l15;
    cbv[nt] = cb[ch]; gv[nt] = lng[ch]; bv2[nt] = lnb[ch]; lwv[nt] = lw[ch];
  }
  #pragma unroll
  for (int mt = 0; mt < 4; mt++)
    #pragma unroll
    for (int r = 0; r < 4; r++) {
      float s = 0.f, s2 = 0.f;
      #pragma unroll
      for (int nt = 0; nt < 4; nt++) {
        float v = fmaxf(acc[mt][nt][r] + cbv[nt], 0.f);
        acc[mt][nt][r] = v;
        s += v; s2 += v * v;
      }
      #pragma unroll
      for (int d = 1; d <= 8; d <<= 1) {
        s += __shfl_xor(s, d, 64);
        s2 += __shfl_xor(s2, d, 64);
      }
      if (l15 == 0) {
        int p = m0 + mt * 16 + quad * 4 + r;
        part_s[p][wv & 3] = s; part_s2[p][wv & 3] = s2;
      }
    }
  __syncthreads();
  if (tid < MT) {
    float s  = part_s[tid][0] + part_s[tid][1] + part_s[tid][2] + part_s[tid][3];
    float s2 = part_s2[tid][0] + part_s2[tid][1] + part_s2[tid][2] + part_s2[tid][3];
    float m = s * (1.f / Fc);
    float var = s2 * (1.f / Fc) - m * m;
    smean[tid] = m; srstd[tid] = rsqrtf(var + EPSc);
  }
  __syncthreads();

  // ---- LN apply + projection reduce ----
  #pragma unroll
  for (int mt = 0; mt < 4; mt++)
    #pragma unroll
    for (int r = 0; r < 4; r++) {
      int p = m0 + mt * 16 + quad * 4 + r;
      float m = smean[p], rs = srstd[p];
      float s = 0.f;
      #pragma unroll
      for (int nt = 0; nt < 4; nt++) {
        float v = (acc[mt][nt][r] - m) * rs * gv[nt] + bv2[nt];
        s += v * lwv[nt];
      }
      #pragma unroll
      for (int d = 1; d <= 8; d <<= 1) s += __shfl_xor(s, d, 64);
      if (l15 == 0) part_p[p][wv & 3] = s;
    }
  __syncthreads();
  if (tid < MT) {
    float o = part_p[tid][0] + part_p[tid][1] + part_p[tid][2] + part_p[tid][3] + lb[0];
    int t = t0 + tid;
    bool masked;
    if (MASK_MEL) masked = !(t < mel_i[b]);
    else          masked = (src_mask[b * N + t] != 0);
    pred[(size_t)b * N + t] = masked ? 0.f : o;
  }
}

// ============================================================
// out = xe + pp*pc2_w + pc2_b + ep*ec2_w + ec2_b  (float4, 4 rows/block)
// ============================================================
__global__ __launch_bounds__(256) void final_kernel(
    const float* __restrict__ x, const int* __restrict__ idx,
    const int* __restrict__ mel_i,
    const float* __restrict__ pp, const float* __restrict__ ep,
    const float* __restrict__ pc2_w, const float* __restrict__ pc2_b,
    const float* __restrict__ ec2_w, const float* __restrict__ ec2_b,
    float* __restrict__ out) {
  int bt = blockIdx.x * 4 + (threadIdx.x >> 6);
  int lane = threadIdx.x & 63;
  int b = bt >> 11, t = bt & (Tc - 1);
  int c4 = lane * 4;
  int i = idx[bt];
  bool val = t < mel_i[b];
  float4 xv = *(const float4*)(x + ((size_t)b * Sc + i) * Hc + c4);
  float p = pp[bt], e = ep[bt];
  float4 pw = *(const float4*)(pc2_w + c4);
  float4 pb = *(const float4*)(pc2_b + c4);
  float4 ew = *(const float4*)(ec2_w + c4);
  float4 eb = *(const float4*)(ec2_b + c4);
  float4 o;
  o.x = (val ? xv.x : 0.f) + p * pw.x + pb.x + e * ew.x + eb.x;
  o.y = (val ? xv.y : 0.f) + p * pw.y + pb.y + e * ew.y + eb.y;
  o.z = (val ? xv.z : 0.f) + p * pw.z + pb.z + e * ew.z + eb.z;
  o.w = (val ? xv.w : 0.f) + p * pw.w + pb.w + e * ew.w + eb.w;
  *(float4*)(out + (size_t)bt * Hc + c4) = o;
}

// ============================================================
extern "C" void kernel_launch(void* const* d_in, const int* in_sizes, int n_in,
                              void* d_out, int out_size, void* d_ws, size_t ws_size,
                              hipStream_t stream) {
  const float* x          = (const float*)d_in[0];
  const unsigned char* sm = (const unsigned char*)d_in[1];
  const float* src_pitch  = (const float*)d_in[3];
  const float* src_energy = (const float*)d_in[4];
  const int*   src_dur    = (const int*)d_in[5];

  const float* dur_cw = (const float*)d_in[7];
  const float* dur_cb = (const float*)d_in[8];
  const float* dur_lng= (const float*)d_in[9];
  const float* dur_lnb= (const float*)d_in[10];
  const float* dur_lw = (const float*)d_in[11];
  const float* dur_lb = (const float*)d_in[12];

  const float* pit_cw = (const float*)d_in[13];
  const float* pit_cb = (const float*)d_in[14];
  const float* pit_lng= (const float*)d_in[15];
  const float* pit_lnb= (const float*)d_in[16];
  const float* pit_lw = (const float*)d_in[17];
  const float* pit_lb = (const float*)d_in[18];

  const float* ene_cw = (const float*)d_in[19];
  const float* ene_cb = (const float*)d_in[20];
  const float* ene_lng= (const float*)d_in[21];
  const float* ene_lnb= (const float*)d_in[22];
  const float* ene_lw = (const float*)d_in[23];
  const float* ene_lb = (const float*)d_in[24];

  const float* pc1_w = (const float*)d_in[25];
  const float* pc1_b = (const float*)d_in[26];
  const float* pc2_w = (const float*)d_in[27];
  const float* pc2_b = (const float*)d_in[28];
  const float* ec1_w = (const float*)d_in[29];
  const float* ec1_b = (const float*)d_in[30];
  const float* ec2_w = (const float*)d_in[31];
  const float* ec2_b = (const float*)d_in[32];

  float* out = (float*)d_out;
  float* o_out   = out + O_OUT;
  float* o_pp    = out + O_PP;
  float* o_ep    = out + O_EP;
  float* o_logd  = out + O_LOGD;
  float* o_dur   = out + O_DUR;
  float* o_mlen  = out + O_MLEN;
  float* o_mmask = out + O_MMASK;

  char* ws = (char*)d_ws;
  int*   w_cum = (int*)(ws + W_CUM);
  int*   w_mel = (int*)(ws + W_MEL);
  int*   w_idx = (int*)(ws + W_IDX);
  short* w_wt  = (short*)(ws + W_WT);
  short* w_bufP = (short*)(ws + W_BUF);
  short* w_bufE = (short*)(ws + W_BUF + BUFB);
  short* w_bufD = (short*)o_out;   // dur intermediate (8.4MB) in o_out (written last)

  // 0) weight prep
  wprep_kernel<<<dim3(24, 8, 6), 256, 0, stream>>>(pit_cw, ene_cw, dur_cw, w_wt);

  // 1) scan + dur/mel_len outputs
  scan_kernel<<<Bc, 64, 0, stream>>>(src_dur, w_cum, w_mel, o_dur, o_mlen);

  // 2) searchsorted + mel_mask output
  idx_kernel<<<(Bc * Tc) / 256, 256, 0, stream>>>(w_cum, w_mel, w_idx, o_mmask);

  dim3 gridT(Tc / MT, Bc);   // 16 x 32 = 512 blocks (2/CU)
  dim3 gridS(Sc / MT, Bc);   // 4 x 32 = 128 blocks

  // 3) pitch predictor
  conv1_mfma_kernel<true><<<gridT, 512, 0, stream>>>(
      x, src_pitch, pc1_w, pc1_b, w_idx, w_mel,
      w_wt + 0 * WTSZ, pit_cb, pit_lng, pit_lnb, w_bufP, Tc);
  // 4) energy predictor layer-1
  conv1_mfma_kernel<true><<<gridT, 512, 0, stream>>>(
      x, src_energy, ec1_w, ec1_b, w_idx, w_mel,
      w_wt + 2 * WTSZ, ene_cb, ene_lng, ene_lnb, w_bufE, Tc);
  // 5) duration predictor layer-1
  conv1_mfma_kernel<false><<<gridS, 512, 0, stream>>>(
      x, nullptr, nullptr, nullptr, nullptr, nullptr,
      w_wt + 4 * WTSZ, dur_cb, dur_lng, dur_lnb, w_bufD, Sc);

  // layer-2 passes
  conv2_proj_mfma_kernel<true><<<gridT, 512, 0, stream>>>(
      w_bufP, w_mel, nullptr,
      w_wt + 1 * WTSZ, pit_cb + Fc, pit_lng + Fc, pit_lnb + Fc,
      pit_lw, pit_lb, o_pp, Tc);
  conv2_proj_mfma_kernel<true><<<gridT, 512, 0, stream>>>(
      w_bufE, w_mel, nullptr,
      w_wt + 3 * WTSZ, ene_cb + Fc, ene_lng + Fc, ene_lnb + Fc,
      ene_lw, ene_lb, o_ep, Tc);
  conv2_proj_mfma_kernel<false><<<gridS, 512, 0, stream>>>(
      w_bufD, nullptr, sm,
      w_wt + 5 * WTSZ, dur_cb + Fc, dur_lng + Fc, dur_lnb + Fc,
      dur_lw, dur_lb, o_logd, Sc);

  // 6) final output
  final_kernel<<<(Bc * Tc) / 4, 256, 0, stream>>>(
      x, w_idx, w_mel, o_pp, o_ep, pc2_w, pc2_b, ec2_w, ec2_b, o_out);
}